// Round 1
// baseline (354.389 us; speedup 1.0000x reference)
//
#include <hip/hip_runtime.h>

// SRU RNN: B=32, T=2000, IN=118, HID=256, OUT=118
// Strategy: per-layer fused kernel. 256 blocks = 32 batches x 8 channel-slices
// (32 ch each). Per 64-step time tile: stage x-tile (bf16) to LDS, MFMA
// U-tile = x @ W_cols (weights held in VGPRs), transpose U into [ch][t] LDS,
// parallel sigmoid phase, serial c-scan on 32 lanes, parallel tanh epilogue,
// write h (bf16) for the next layer. Final GEMM h1 @ Wout + bout in fp32 out.

typedef __attribute__((ext_vector_type(8))) __bf16 bf16x8;
typedef __attribute__((ext_vector_type(4))) float f32x4;
typedef __attribute__((ext_vector_type(4))) unsigned int u32x4;

static __device__ __forceinline__ float sigmoid_f(float x) {
    return 1.f / (1.f + __expf(-x));
}
static __device__ __forceinline__ float tanh_f(float x) {
    float e = __expf(-2.f * fabsf(x));
    float t = (1.f - e) / (1.f + e);
    return copysignf(t, x);
}
static __device__ __forceinline__ unsigned short f2bf(float f) {
    union { float f; unsigned u; } v; v.f = f;
    return (unsigned short)((v.u + 0x7fffu + ((v.u >> 16) & 1u)) >> 16);
}
static __device__ __forceinline__ float bf2f(unsigned short h) {
    union { unsigned u; float f; } v; v.u = ((unsigned)h) << 16;
    return v.f;
}

static constexpr int NB = 32;       // batch
static constexpr int T  = 2000;     // time
static constexpr int DH = 256;      // hidden

// ---------------- prep: x fp32 -> bf16 padded [64000][128] ----------------
__global__ void prep_x_kernel(const float* __restrict__ x, unsigned short* __restrict__ xp) {
    int i = blockIdx.x * 256 + threadIdx.x;            // 64000*128
    if (i >= 64000 * 128) return;
    int row = i >> 7, k = i & 127;
    float v = (k < 118) ? x[row * 118 + k] : 0.f;
    xp[i] = f2bf(v);
}

// ---------------- prep: weights transposed+padded to bf16 ----------------
// W0t [1024][128], W1t [768][256], Woutt [128][256]
__global__ void prep_w_kernel(const float* __restrict__ W0, const float* __restrict__ W1,
                              const float* __restrict__ Wout,
                              unsigned short* __restrict__ W0t, unsigned short* __restrict__ W1t,
                              unsigned short* __restrict__ Wot) {
    int i = blockIdx.x * 256 + threadIdx.x;
    if (i < 1024 * 128) {
        int n = i >> 7, k = i & 127;
        float v = (k < 118) ? W0[k * 1024 + n] : 0.f;
        W0t[i] = f2bf(v);
        return;
    }
    i -= 1024 * 128;
    if (i < 768 * 256) {
        int n = i >> 8, k = i & 255;
        W1t[i] = f2bf(W1[k * 768 + n]);
        return;
    }
    i -= 768 * 256;
    if (i < 128 * 256) {
        int n = i >> 8, k = i & 255;
        float v = (n < 118) ? Wout[k * 118 + n] : 0.f;
        Wot[i] = f2bf(v);
    }
}

// ---------------- fused SRU layer ----------------
// xin:  [NB][T][KP] bf16 (zero-padded K)
// Wt:   [KFAC*256][KP] bf16, row n = output column n of W (transposed), K padded
// bvec: [512] fp32 (b_f = [0:256), b_r = [256:512))
// hout: [NB][T][256] bf16
template <int KP, int KFAC>
__global__ __launch_bounds__(256, 1)
void sru_layer_kernel(const unsigned short* __restrict__ xin,
                      const unsigned short* __restrict__ Wt,
                      const float* __restrict__ bvec,
                      unsigned short* __restrict__ hout) {
    constexpr int TT    = 64;
    constexpr int NTIL  = (T + TT - 1) / TT;   // 32 (last tile = 16 steps)
    constexpr int NCOLS = KFAC * 32;           // 128 or 96
    constexpr int NTN   = NCOLS / 16;          // 8 or 6
    constexpr int KST   = KP / 32;             // 4 or 8
    constexpr int LDA   = KP + 8;              // bf16 elems per sA row (16B-aligned, 2-way banks)
    constexpr int LDU   = TT + 4;              // f32 per sU row

    __shared__ unsigned short sA[TT * LDA];    // x tile [t][k]
    __shared__ float sU[NCOLS * LDU];          // U^T [n][t]; rows: [0,32)=x~/g/c [32,64)=f [64,96)=r [96,128)=hw

    const int tid  = threadIdx.x;
    const int lane = tid & 63;
    const int w    = tid >> 6;
    const int b    = blockIdx.x >> 3;
    const int d0   = (blockIdx.x & 7) * 32;

    // ---- load weight fragments into registers (shared by the whole tile loop) ----
    bf16x8 bfrag[NTN][KST];
    {
        const int nl = lane & 15;
        const int kq = (lane >> 4) * 8;
#pragma unroll
        for (int nt = 0; nt < NTN; ++nt) {
            const int n_loc = nt * 16 + nl;
            const int wrow  = (n_loc >> 5) * 256 + d0 + (n_loc & 31);
            const unsigned short* src = Wt + wrow * KP + kq;
#pragma unroll
            for (int ks = 0; ks < KST; ++ks)
                bfrag[nt][ks] = *(const bf16x8*)(src + ks * 32);
        }
    }

    const int ch4 = tid >> 3;                  // activation-phase channel (0..31)
    const float bf_ = bvec[d0 + ch4];
    const float br_ = bvec[256 + d0 + ch4];

    const unsigned short* xb = xin + (size_t)b * T * KP;
    unsigned short* hb = hout + (size_t)b * T * 256;

    float c = 0.f;                             // scan state (lanes tid<32)

    for (int it = 0; it < NTIL; ++it) {
        const int t0g = it * TT;
        const int ttcur = (T - t0g < TT) ? (T - t0g) : TT;

        __syncthreads();                       // previous epilogue done (sA/sU reuse)

        // ---- stage x tile -> sA ----
        {
            constexpr int CPR = KP / 8;        // 16B chunks per row
            constexpr int TOT = TT * CPR;      // multiple of 256
            u32x4 zero = {0u, 0u, 0u, 0u};
#pragma unroll
            for (int base = 0; base < TOT; base += 256) {
                int idx = base + tid;
                int r = idx / CPR, cc = idx % CPR;
                int tg = t0g + r;
                u32x4 v = (tg < T) ? *(const u32x4*)(xb + (size_t)tg * KP + cc * 8) : zero;
                *(u32x4*)(&sA[r * LDA + cc * 8]) = v;
            }
        }
        __syncthreads();

        // ---- GEMM: wave w computes rows 16w..16w+15 of the U tile ----
        f32x4 acc[NTN];
        f32x4 fz = {0.f, 0.f, 0.f, 0.f};
#pragma unroll
        for (int nt = 0; nt < NTN; ++nt) acc[nt] = fz;
        {
            const unsigned short* arow = &sA[(16 * w + (lane & 15)) * LDA + (lane >> 4) * 8];
#pragma unroll
            for (int ks = 0; ks < KST; ++ks) {
                bf16x8 a = *(const bf16x8*)(arow + ks * 32);
#pragma unroll
                for (int nt = 0; nt < NTN; ++nt)
                    acc[nt] = __builtin_amdgcn_mfma_f32_16x16x32_bf16(a, bfrag[nt][ks], acc[nt], 0, 0, 0);
            }
        }
        // write U^T: D frag (col=lane&15, row=4*(lane>>4)+j) -> sU[n][t], b128 each
        {
            const int nl = lane & 15;
            const int trow = 16 * w + (lane >> 4) * 4;
#pragma unroll
            for (int nt = 0; nt < NTN; ++nt)
                *(f32x4*)&sU[(nt * 16 + nl) * LDU + trow] = acc[nt];
        }
        __syncthreads();

        // ---- activation phase: f=sig(Uf+bf), g=(1-f)*x~, r=sig(Ur+br) ----
        {
            const int t0 = (tid & 7) * 8;
            float* xrow = &sU[ch4 * LDU + t0];
            float* frow = &sU[(32 + ch4) * LDU + t0];
            float* rrow = &sU[(64 + ch4) * LDU + t0];
#pragma unroll
            for (int j = 0; j < 8; ++j) {
                float f = sigmoid_f(frow[j] + bf_);
                float g = (1.f - f) * xrow[j];
                frow[j] = f;
                xrow[j] = g;
                rrow[j] = sigmoid_f(rrow[j] + br_);
            }
        }
        __syncthreads();

        // ---- serial scan, 32 lanes (one per channel), c kept in register ----
        if (tid < 32) {
            float cc = c;
            float* grow = &sU[tid * LDU];
            float* frow = &sU[(32 + tid) * LDU];
            for (int t4 = 0; t4 < ttcur; t4 += 4) {
                f32x4 f4 = *(f32x4*)&frow[t4];
                f32x4 g4 = *(f32x4*)&grow[t4];
                f32x4 c4;
                cc = f4.x * cc + g4.x; c4.x = cc;
                cc = f4.y * cc + g4.y; c4.y = cc;
                cc = f4.z * cc + g4.z; c4.z = cc;
                cc = f4.w * cc + g4.w; c4.w = cc;
                *(f32x4*)&grow[t4] = c4;       // c overwrites g
            }
            c = cc;
        }
        __syncthreads();

        // ---- epilogue: h = r*tanh(c) + (1-r)*x_hw; store bf16 (coalesced in ch) ----
        {
            const int ch = tid & 31;
            const int tb = tid >> 5;
#pragma unroll
            for (int p = 0; p < 8; ++p) {
                int t = tb + p * 8;
                if (t < ttcur) {
                    float cv = sU[ch * LDU + t];
                    float rv = sU[(64 + ch) * LDU + t];
                    float xhw;
                    if constexpr (KFAC == 4)
                        xhw = sU[(96 + ch) * LDU + t];
                    else
                        xhw = bf2f(sA[t * LDA + d0 + ch]);
                    float h = rv * tanh_f(cv) + (1.f - rv) * xhw;
                    hb[(size_t)(t0g + t) * 256 + d0 + ch] = f2bf(h);
                }
            }
        }
    }
}

// ---------------- output GEMM: out[64000][118] = h1[64000][256] @ Wout + bout ----------------
__global__ __launch_bounds__(256, 2)
void out_gemm_kernel(const unsigned short* __restrict__ h1,
                     const unsigned short* __restrict__ Wt,   // [128][256] (transposed, n-padded)
                     const float* __restrict__ bout,
                     float* __restrict__ out) {
    constexpr int K = 256, LDA = 264;
    const int tid = threadIdx.x, lane = tid & 63, w = tid >> 6;
    const int m0 = (blockIdx.x >> 1) * 64;
    const int n0 = (blockIdx.x & 1) * 64;

    __shared__ unsigned short sA[64 * LDA];

    bf16x8 bfrag[4][8];
    {
        const int nl = lane & 15, kq = (lane >> 4) * 8;
#pragma unroll
        for (int nt = 0; nt < 4; ++nt) {
            const unsigned short* src = Wt + (n0 + nt * 16 + nl) * K + kq;
#pragma unroll
            for (int ks = 0; ks < 8; ++ks)
                bfrag[nt][ks] = *(const bf16x8*)(src + ks * 32);
        }
    }
    {
#pragma unroll
        for (int base = 0; base < 2048; base += 256) {
            int idx = base + tid;
            int r = idx >> 5, cc = idx & 31;
            *(u32x4*)&sA[r * LDA + cc * 8] = *(const u32x4*)(h1 + (size_t)(m0 + r) * K + cc * 8);
        }
    }
    __syncthreads();

    f32x4 acc[4];
    f32x4 fz = {0.f, 0.f, 0.f, 0.f};
#pragma unroll
    for (int nt = 0; nt < 4; ++nt) acc[nt] = fz;
    {
        const unsigned short* arow = &sA[(16 * w + (lane & 15)) * LDA + (lane >> 4) * 8];
#pragma unroll
        for (int ks = 0; ks < 8; ++ks) {
            bf16x8 a = *(const bf16x8*)(arow + ks * 32);
#pragma unroll
            for (int nt = 0; nt < 4; ++nt)
                acc[nt] = __builtin_amdgcn_mfma_f32_16x16x32_bf16(a, bfrag[nt][ks], acc[nt], 0, 0, 0);
        }
    }
    {
        const int nl = lane & 15;
        const int rbase = m0 + 16 * w + (lane >> 4) * 4;
#pragma unroll
        for (int nt = 0; nt < 4; ++nt) {
            int col = n0 + nt * 16 + nl;
            if (col < 118) {
                float bo = bout[col];
#pragma unroll
                for (int j = 0; j < 4; ++j)
                    out[(size_t)(rbase + j) * 118 + col] = acc[nt][j] + bo;
            }
        }
    }
}

extern "C" void kernel_launch(void* const* d_in, const int* in_sizes, int n_in,
                              void* d_out, int out_size, void* d_ws, size_t ws_size,
                              hipStream_t stream) {
    const float* seq  = (const float*)d_in[0];
    // d_in[1] = lengths: unused by the reference
    const float* W0   = (const float*)d_in[2];
    const float* b0   = (const float*)d_in[3];
    const float* W1   = (const float*)d_in[4];
    const float* b1   = (const float*)d_in[5];
    const float* Wout = (const float*)d_in[6];
    const float* bout = (const float*)d_in[7];
    float* out = (float*)d_out;

    char* ws = (char*)d_ws;
    size_t off = 0;
    auto alloc = [&](size_t bytes) -> void* {
        void* p = ws + off;
        off = (off + bytes + 255) & ~(size_t)255;
        return p;
    };
    unsigned short* x0p = (unsigned short*)alloc(64000ull * 128 * 2);
    unsigned short* h0b = (unsigned short*)alloc(64000ull * 256 * 2);
    unsigned short* h1b = (unsigned short*)alloc(64000ull * 256 * 2);
    unsigned short* W0t = (unsigned short*)alloc(1024ull * 128 * 2);
    unsigned short* W1t = (unsigned short*)alloc(768ull * 256 * 2);
    unsigned short* Wot = (unsigned short*)alloc(128ull * 256 * 2);
    if (ws_size < off) return;  // workspace too small: bail (avoids corruption)

    prep_x_kernel<<<dim3(32000), dim3(256), 0, stream>>>(seq, x0p);
    prep_w_kernel<<<dim3(1408), dim3(256), 0, stream>>>(W0, W1, Wout, W0t, W1t, Wot);
    sru_layer_kernel<128, 4><<<dim3(256), dim3(256), 0, stream>>>(x0p, W0t, b0, h0b);
    sru_layer_kernel<256, 3><<<dim3(256), dim3(256), 0, stream>>>(h0b, W1t, b1, h1b);
    out_gemm_kernel<<<dim3(2000), dim3(256), 0, stream>>>(h1b, Wot, bout, out);
}

// Round 2
// 217.486 us; speedup vs baseline: 1.6295x; 1.6295x over previous
//
#include <hip/hip_runtime.h>

// SRU RNN: B=32, T=2000, IN=118, HID=256, OUT=118
// Round 2: 512 blocks (32 batches x 16 channel-slices of 16 ch), 2 blocks/CU.
// Same-batch blocks share one XCD (id ≡ b mod 8) so x/h tiles are L2-shared.
// Activation computed in-register on MFMA fragments (no act phase), r kept in
// regs, only f,g round-trip LDS for the serial scan. Next tile's x staged
// async into registers at tile top, ds_written at tile bottom. 3 barriers/tile.

typedef __attribute__((ext_vector_type(8))) __bf16 bf16x8;
typedef __attribute__((ext_vector_type(4))) float f32x4;
typedef __attribute__((ext_vector_type(4))) unsigned int u32x4;

static __device__ __forceinline__ float sigmoid_f(float x) {
    return 1.f / (1.f + __expf(-x));
}
static __device__ __forceinline__ float tanh_f(float x) {
    float e = __expf(-2.f * fabsf(x));
    float t = (1.f - e) / (1.f + e);
    return copysignf(t, x);
}
static __device__ __forceinline__ unsigned short f2bf(float f) {
    union { float f; unsigned u; } v; v.f = f;
    return (unsigned short)((v.u + 0x7fffu + ((v.u >> 16) & 1u)) >> 16);
}
static __device__ __forceinline__ float bf2f(unsigned short h) {
    union { unsigned u; float f; } v; v.u = ((unsigned)h) << 16;
    return v.f;
}

static constexpr int T = 2000;

// ---------------- prep: x fp32 -> bf16 padded [64000][128] ----------------
__global__ void prep_x_kernel(const float* __restrict__ x, unsigned short* __restrict__ xp) {
    int i = blockIdx.x * 256 + threadIdx.x;            // 64000*128
    if (i >= 64000 * 128) return;
    int row = i >> 7, k = i & 127;
    float v = (k < 118) ? x[row * 118 + k] : 0.f;
    xp[i] = f2bf(v);
}

// ---------------- prep: weights transposed+padded to bf16 ----------------
// W0t [1024][128], W1t [768][256], Woutt [128][256]
__global__ void prep_w_kernel(const float* __restrict__ W0, const float* __restrict__ W1,
                              const float* __restrict__ Wout,
                              unsigned short* __restrict__ W0t, unsigned short* __restrict__ W1t,
                              unsigned short* __restrict__ Wot) {
    int i = blockIdx.x * 256 + threadIdx.x;
    if (i < 1024 * 128) {
        int n = i >> 7, k = i & 127;
        float v = (k < 118) ? W0[k * 1024 + n] : 0.f;
        W0t[i] = f2bf(v);
        return;
    }
    i -= 1024 * 128;
    if (i < 768 * 256) {
        int n = i >> 8, k = i & 255;
        W1t[i] = f2bf(W1[k * 768 + n]);
        return;
    }
    i -= 768 * 256;
    if (i < 128 * 256) {
        int n = i >> 8, k = i & 255;
        float v = (n < 118) ? Wout[k * 118 + n] : 0.f;
        Wot[i] = f2bf(v);
    }
}

// ---------------- fused SRU layer ----------------
// xin:  [32][T][KP] bf16 (zero-padded K)
// Wt:   [KFAC*256][KP] bf16, row n = output column n of W (transposed)
// bvec: [512] fp32 (b_f [0:256), b_r [256:512))
// hout: [32][T][256] bf16
// grid: 512 blocks; block id = slice*32 + b  (same-batch blocks -> same XCD)
template <int KP, int KFAC>
__global__ __launch_bounds__(256, 2)
void sru_layer_kernel(const unsigned short* __restrict__ xin,
                      const unsigned short* __restrict__ Wt,
                      const float* __restrict__ bvec,
                      unsigned short* __restrict__ hout) {
    constexpr int TT   = 64;
    constexpr int NTIL = (T + TT - 1) / TT;     // 32 (last tile = 16 steps)
    constexpr int KST  = KP / 32;               // 4 or 8 k-steps
    constexpr int LDA  = KP + 8;                // bf16 per sA row (row stride 16B-offset banks)
    constexpr int LDU  = TT + 4;                // f32 per sU row
    constexpr int CPR  = KP / 8;                // 16B chunks per x row (16 or 32)
    constexpr int NLD  = TT * CPR / 256;        // chunks per thread (4 or 8)

    __shared__ unsigned short sA[TT * LDA];     // x tile [t][k]
    __shared__ float sU[32 * LDU];              // rows [0,16)=g then c; [16,32)=f

    const int tid  = threadIdx.x;
    const int lane = tid & 63;
    const int w    = tid >> 6;
    const int b    = blockIdx.x & 31;
    const int d0   = (blockIdx.x >> 5) * 16;

    const int nl   = lane & 15;                 // channel within slice / frag col
    const int kq   = (lane >> 4) * 8;           // k offset within 32-k step
    const int trow = 16 * w + (lane >> 4) * 4;  // t base this lane covers (C/D frag rows)

    // ---- weight fragments in registers ----
    bf16x8 bfrag[KFAC][KST];
#pragma unroll
    for (int nt = 0; nt < KFAC; ++nt) {
        const unsigned short* src = Wt + (size_t)(nt * 256 + d0 + nl) * KP + kq;
#pragma unroll
        for (int ks = 0; ks < KST; ++ks)
            bfrag[nt][ks] = *(const bf16x8*)(src + ks * 32);
    }
    const float bf_r = bvec[d0 + nl];
    const float br_r = bvec[256 + d0 + nl];

    const unsigned short* xb = xin + (size_t)b * T * KP;
    unsigned short* hb = hout + (size_t)b * T * 256;

    // ---- prologue: stage tile 0 ----
    u32x4 xreg[NLD];
    const u32x4 zero4 = {0u, 0u, 0u, 0u};
#pragma unroll
    for (int j = 0; j < NLD; ++j) {
        int idx = j * 256 + tid;
        int r = idx / CPR, cc = idx % CPR;
        xreg[j] = (r < T) ? *(const u32x4*)(xb + (size_t)r * KP + cc * 8) : zero4;
    }
#pragma unroll
    for (int j = 0; j < NLD; ++j) {
        int idx = j * 256 + tid;
        int r = idx / CPR, cc = idx % CPR;
        *(u32x4*)(&sA[r * LDA + cc * 8]) = xreg[j];
    }

    float c = 0.f;                              // scan state (tid<16)

    for (int it = 0; it < NTIL; ++it) {
        const int t0g = it * TT;
        const int ttcur = (T - t0g < TT) ? (T - t0g) : TT;

        __syncthreads();                        // sA staged, sU free

        // ---- issue async loads for next tile (held in regs until tile end) ----
        if (it + 1 < NTIL) {
#pragma unroll
            for (int j = 0; j < NLD; ++j) {
                int idx = j * 256 + tid;
                int r = idx / CPR, cc = idx % CPR;
                int tg = t0g + TT + r;
                xreg[j] = (tg < T) ? *(const u32x4*)(xb + (size_t)tg * KP + cc * 8) : zero4;
            }
        }

        // ---- GEMM: U fragments for this wave's 16 t-rows ----
        f32x4 acc[KFAC];
        const f32x4 fz = {0.f, 0.f, 0.f, 0.f};
#pragma unroll
        for (int nt = 0; nt < KFAC; ++nt) acc[nt] = fz;
        {
            const unsigned short* arow = &sA[(16 * w + nl) * LDA + kq];
#pragma unroll
            for (int ks = 0; ks < KST; ++ks) {
                bf16x8 a = *(const bf16x8*)(arow + ks * 32);
#pragma unroll
                for (int nt = 0; nt < KFAC; ++nt)
                    acc[nt] = __builtin_amdgcn_mfma_f32_16x16x32_bf16(a, bfrag[nt][ks], acc[nt], 0, 0, 0);
            }
        }

        // ---- in-register activation; only f,g go to LDS ----
        f32x4 fv, gv, rv;
#pragma unroll
        for (int j = 0; j < 4; ++j) {
            float f = sigmoid_f(acc[1][j] + bf_r);
            fv[j] = f;
            gv[j] = (1.f - f) * acc[0][j];
            rv[j] = sigmoid_f(acc[2][j] + br_r);
        }
        *(f32x4*)&sU[nl * LDU + trow]        = gv;
        *(f32x4*)&sU[(16 + nl) * LDU + trow] = fv;
        __syncthreads();

        // ---- serial scan: 16 lanes, one per channel; c overwrites g ----
        if (tid < 16) {
            float cc = c;
            float* grow = &sU[tid * LDU];
            float* frow = &sU[(16 + tid) * LDU];
            for (int t4 = 0; t4 < ttcur; t4 += 4) {
                f32x4 f4 = *(f32x4*)&frow[t4];
                f32x4 g4 = *(f32x4*)&grow[t4];
                f32x4 c4;
                cc = f4.x * cc + g4.x; c4.x = cc;
                cc = f4.y * cc + g4.y; c4.y = cc;
                cc = f4.z * cc + g4.z; c4.z = cc;
                cc = f4.w * cc + g4.w; c4.w = cc;
                *(f32x4*)&grow[t4] = c4;
            }
            c = cc;
        }
        __syncthreads();

        // ---- epilogue (frag-mapped): h = r*tanh(c) + (1-r)*xhw ----
        {
            f32x4 cv = *(f32x4*)&sU[nl * LDU + trow];
#pragma unroll
            for (int j = 0; j < 4; ++j) {
                int t = trow + j;
                if (t < ttcur) {
                    float xhw;
                    if constexpr (KFAC == 4)
                        xhw = acc[3][j];
                    else
                        xhw = bf2f(xb[(size_t)(t0g + t) * KP + d0 + nl]);  // L2-hot
                    float h = rv[j] * tanh_f(cv[j]) + (1.f - rv[j]) * xhw;
                    hb[(size_t)(t0g + t) * 256 + d0 + nl] = f2bf(h);
                }
            }
        }

        // ---- commit next tile to sA (sA readers all finished pre-scan) ----
        if (it + 1 < NTIL) {
#pragma unroll
            for (int j = 0; j < NLD; ++j) {
                int idx = j * 256 + tid;
                int r = idx / CPR, cc = idx % CPR;
                *(u32x4*)(&sA[r * LDA + cc * 8]) = xreg[j];
            }
        }
    }
}

// ---------------- output GEMM: out[64000][118] = h1[64000][256] @ Wout + bout ----------------
__global__ __launch_bounds__(256, 2)
void out_gemm_kernel(const unsigned short* __restrict__ h1,
                     const unsigned short* __restrict__ Wt,   // [128][256] (transposed, n-padded)
                     const float* __restrict__ bout,
                     float* __restrict__ out) {
    constexpr int K = 256, LDA = 264;
    const int tid = threadIdx.x, lane = tid & 63, w = tid >> 6;
    const int m0 = (blockIdx.x >> 1) * 64;
    const int n0 = (blockIdx.x & 1) * 64;

    __shared__ unsigned short sA[64 * LDA];

    bf16x8 bfrag[4][8];
    {
        const int nl = lane & 15, kq = (lane >> 4) * 8;
#pragma unroll
        for (int nt = 0; nt < 4; ++nt) {
            const unsigned short* src = Wt + (n0 + nt * 16 + nl) * K + kq;
#pragma unroll
            for (int ks = 0; ks < 8; ++ks)
                bfrag[nt][ks] = *(const bf16x8*)(src + ks * 32);
        }
    }
    {
#pragma unroll
        for (int base = 0; base < 2048; base += 256) {
            int idx = base + tid;
            int r = idx >> 5, cc = idx & 31;
            *(u32x4*)&sA[r * LDA + cc * 8] = *(const u32x4*)(h1 + (size_t)(m0 + r) * K + cc * 8);
        }
    }
    __syncthreads();

    f32x4 acc[4];
    f32x4 fz = {0.f, 0.f, 0.f, 0.f};
#pragma unroll
    for (int nt = 0; nt < 4; ++nt) acc[nt] = fz;
    {
        const unsigned short* arow = &sA[(16 * w + (lane & 15)) * LDA + (lane >> 4) * 8];
#pragma unroll
        for (int ks = 0; ks < 8; ++ks) {
            bf16x8 a = *(const bf16x8*)(arow + ks * 32);
#pragma unroll
            for (int nt = 0; nt < 4; ++nt)
                acc[nt] = __builtin_amdgcn_mfma_f32_16x16x32_bf16(a, bfrag[nt][ks], acc[nt], 0, 0, 0);
        }
    }
    {
        const int nl = lane & 15;
        const int rbase = m0 + 16 * w + (lane >> 4) * 4;
#pragma unroll
        for (int nt = 0; nt < 4; ++nt) {
            int col = n0 + nt * 16 + nl;
            if (col < 118) {
                float bo = bout[col];
#pragma unroll
                for (int j = 0; j < 4; ++j)
                    out[(size_t)(rbase + j) * 118 + col] = acc[nt][j] + bo;
            }
        }
    }
}

extern "C" void kernel_launch(void* const* d_in, const int* in_sizes, int n_in,
                              void* d_out, int out_size, void* d_ws, size_t ws_size,
                              hipStream_t stream) {
    const float* seq  = (const float*)d_in[0];
    // d_in[1] = lengths: unused by the reference
    const float* W0   = (const float*)d_in[2];
    const float* b0   = (const float*)d_in[3];
    const float* W1   = (const float*)d_in[4];
    const float* b1   = (const float*)d_in[5];
    const float* Wout = (const float*)d_in[6];
    const float* bout = (const float*)d_in[7];
    float* out = (float*)d_out;

    char* ws = (char*)d_ws;
    size_t off = 0;
    auto alloc = [&](size_t bytes) -> void* {
        void* p = ws + off;
        off = (off + bytes + 255) & ~(size_t)255;
        return p;
    };
    unsigned short* x0p = (unsigned short*)alloc(64000ull * 128 * 2);
    unsigned short* h0b = (unsigned short*)alloc(64000ull * 256 * 2);
    unsigned short* h1b = (unsigned short*)alloc(64000ull * 256 * 2);
    unsigned short* W0t = (unsigned short*)alloc(1024ull * 128 * 2);
    unsigned short* W1t = (unsigned short*)alloc(768ull * 256 * 2);
    unsigned short* Wot = (unsigned short*)alloc(128ull * 256 * 2);
    if (ws_size < off) return;  // workspace too small: bail

    prep_x_kernel<<<dim3(32000), dim3(256), 0, stream>>>(seq, x0p);
    prep_w_kernel<<<dim3(1408), dim3(256), 0, stream>>>(W0, W1, Wout, W0t, W1t, Wot);
    sru_layer_kernel<128, 4><<<dim3(512), dim3(256), 0, stream>>>(x0p, W0t, b0, h0b);
    sru_layer_kernel<256, 3><<<dim3(512), dim3(256), 0, stream>>>(h0b, W1t, b1, h1b);
    out_gemm_kernel<<<dim3(2000), dim3(256), 0, stream>>>(h1b, Wot, bout, out);
}

// Round 3
// 186.659 us; speedup vs baseline: 1.8986x; 1.1652x over previous
//
#include <hip/hip_runtime.h>

// SRU RNN: B=32, T=2000, IN=118, HID=256, OUT=118
// Round 3: wave-parallel affine scan. c_t = f_t*c_{t-1} + g_t is composition
// of affine maps (F,G). Per 64-t tile: each lane composes its 4 maps in-reg,
// Kogge-Stone across the 4 t-quads via shfl_up, 16B/wave summary through LDS,
// exclusive-compose across the 4 waves, apply. No serial phase, no sU buffer,
// 2 barriers/tile. f/g/r/c never leave registers.

typedef __attribute__((ext_vector_type(8))) __bf16 bf16x8;
typedef __attribute__((ext_vector_type(4))) float f32x4;
typedef __attribute__((ext_vector_type(4))) unsigned int u32x4;

static __device__ __forceinline__ float sigmoid_f(float x) {
    return 1.f / (1.f + __expf(-x));
}
static __device__ __forceinline__ float tanh_f(float x) {
    float e = __expf(-2.f * fabsf(x));
    float t = (1.f - e) / (1.f + e);
    return copysignf(t, x);
}
static __device__ __forceinline__ unsigned short f2bf(float f) {
    union { float f; unsigned u; } v; v.f = f;
    return (unsigned short)((v.u + 0x7fffu + ((v.u >> 16) & 1u)) >> 16);
}
static __device__ __forceinline__ float bf2f(unsigned short h) {
    union { unsigned u; float f; } v; v.u = ((unsigned)h) << 16;
    return v.f;
}

static constexpr int T = 2000;

// ---------------- prep: x fp32 -> bf16 padded [64000][128] ----------------
__global__ void prep_x_kernel(const float* __restrict__ x, unsigned short* __restrict__ xp) {
    int i = blockIdx.x * 256 + threadIdx.x;            // 64000*128
    if (i >= 64000 * 128) return;
    int row = i >> 7, k = i & 127;
    float v = (k < 118) ? x[row * 118 + k] : 0.f;
    xp[i] = f2bf(v);
}

// ---------------- prep: weights transposed+padded to bf16 ----------------
__global__ void prep_w_kernel(const float* __restrict__ W0, const float* __restrict__ W1,
                              const float* __restrict__ Wout,
                              unsigned short* __restrict__ W0t, unsigned short* __restrict__ W1t,
                              unsigned short* __restrict__ Wot) {
    int i = blockIdx.x * 256 + threadIdx.x;
    if (i < 1024 * 128) {
        int n = i >> 7, k = i & 127;
        float v = (k < 118) ? W0[k * 1024 + n] : 0.f;
        W0t[i] = f2bf(v);
        return;
    }
    i -= 1024 * 128;
    if (i < 768 * 256) {
        int n = i >> 8, k = i & 255;
        W1t[i] = f2bf(W1[k * 768 + n]);
        return;
    }
    i -= 768 * 256;
    if (i < 128 * 256) {
        int n = i >> 8, k = i & 255;
        float v = (n < 118) ? Wout[k * 118 + n] : 0.f;
        Wot[i] = f2bf(v);
    }
}

// ---------------- fused SRU layer ----------------
// xin:  [32][T][KP] bf16 (zero-padded K)
// Wt:   [KFAC*256][KP] bf16, row n = output column n of W (transposed)
// bvec: [512] fp32 (b_f [0:256), b_r [256:512))
// hout: [32][T][256] bf16
// grid: 512; block id = slice*32 + b  (same-batch blocks -> same XCD)
template <int KP, int KFAC>
__global__ __launch_bounds__(256, 2)
void sru_layer_kernel(const unsigned short* __restrict__ xin,
                      const unsigned short* __restrict__ Wt,
                      const float* __restrict__ bvec,
                      unsigned short* __restrict__ hout) {
    constexpr int TT   = 64;
    constexpr int NTIL = (T + TT - 1) / TT;     // 32 (last tile = 16 steps)
    constexpr int KST  = KP / 32;               // 4 or 8 k-steps
    constexpr int LDA  = KP + 8;                // bf16 per sA row
    constexpr int CPR  = KP / 8;                // 16B chunks per x row
    constexpr int NLD  = TT * CPR / 256;        // chunks per thread

    __shared__ unsigned short sA[TT * LDA];     // x tile [t][k]
    __shared__ float2 sSum[4][16];              // per-wave scan summary (F,G)

    const int tid  = threadIdx.x;
    const int lane = tid & 63;
    const int w    = tid >> 6;
    const int b    = blockIdx.x & 31;
    const int d0   = (blockIdx.x >> 5) * 16;

    const int nl   = lane & 15;                 // channel within slice / frag col
    const int q    = lane >> 4;                 // t-quad within wave
    const int kq   = q * 8;                     // k offset within 32-k step
    const int trow = 16 * w + q * 4;            // first t this lane covers

    // ---- weight fragments in registers ----
    bf16x8 bfrag[KFAC][KST];
#pragma unroll
    for (int nt = 0; nt < KFAC; ++nt) {
        const unsigned short* src = Wt + (size_t)(nt * 256 + d0 + nl) * KP + kq;
#pragma unroll
        for (int ks = 0; ks < KST; ++ks)
            bfrag[nt][ks] = *(const bf16x8*)(src + ks * 32);
    }
    const float bf_r = bvec[d0 + nl];
    const float br_r = bvec[256 + d0 + nl];

    const unsigned short* xb = xin + (size_t)b * T * KP;
    unsigned short* hb = hout + (size_t)b * T * 256;

    // ---- prologue: stage tile 0 ----
    u32x4 xreg[NLD];
    const u32x4 zero4 = {0u, 0u, 0u, 0u};
#pragma unroll
    for (int j = 0; j < NLD; ++j) {
        int idx = j * 256 + tid;
        int r = idx / CPR, cc = idx % CPR;
        xreg[j] = *(const u32x4*)(xb + (size_t)r * KP + cc * 8);
    }
#pragma unroll
    for (int j = 0; j < NLD; ++j) {
        int idx = j * 256 + tid;
        int r = idx / CPR, cc = idx % CPR;
        *(u32x4*)(&sA[r * LDA + cc * 8]) = xreg[j];
    }

    float c_in = 0.f;                           // running c for channel nl

    for (int it = 0; it < NTIL; ++it) {
        const int t0g = it * TT;
        const int ttcur = (T - t0g < TT) ? (T - t0g) : TT;

        __syncthreads();                        // (A) sA committed, sSum free

        // ---- issue next tile's loads (held in regs until tile end) ----
        if (it + 1 < NTIL) {
#pragma unroll
            for (int j = 0; j < NLD; ++j) {
                int idx = j * 256 + tid;
                int r = idx / CPR, cc = idx % CPR;
                int tg = t0g + TT + r;
                xreg[j] = (tg < T) ? *(const u32x4*)(xb + (size_t)tg * KP + cc * 8) : zero4;
            }
        }
        // ---- issue xhw re-reads early (layer KFAC==3 only; L2-hot) ----
        unsigned short xhw_raw[4];
        if constexpr (KFAC == 3) {
#pragma unroll
            for (int j = 0; j < 4; ++j) {
                int t = trow + j;
                xhw_raw[j] = xb[(size_t)(t0g + t) * KP + d0 + nl];
            }
        }

        // ---- GEMM: U fragments for this wave's 16 t-rows ----
        f32x4 acc[KFAC];
        const f32x4 fz = {0.f, 0.f, 0.f, 0.f};
#pragma unroll
        for (int nt = 0; nt < KFAC; ++nt) acc[nt] = fz;
        {
            const unsigned short* arow = &sA[(16 * w + nl) * LDA + kq];
#pragma unroll
            for (int ks = 0; ks < KST; ++ks) {
                bf16x8 a = *(const bf16x8*)(arow + ks * 32);
#pragma unroll
                for (int nt = 0; nt < KFAC; ++nt)
                    acc[nt] = __builtin_amdgcn_mfma_f32_16x16x32_bf16(a, bfrag[nt][ks], acc[nt], 0, 0, 0);
            }
        }

        // ---- in-register activation ----
        f32x4 fv, gv, rv;
#pragma unroll
        for (int j = 0; j < 4; ++j) {
            float f = sigmoid_f(acc[1][j] + bf_r);
            fv[j] = f;
            gv[j] = (1.f - f) * acc[0][j];
            rv[j] = sigmoid_f(acc[2][j] + br_r);
        }

        // ---- local affine compose over this lane's 4 t's ----
        float F = fv[0] * fv[1];
        float G = gv[0];
        G = __builtin_fmaf(fv[1], G, gv[1]);
        G = __builtin_fmaf(fv[2], G, gv[2]);
        G = __builtin_fmaf(fv[3], G, gv[3]);
        F = F * fv[2] * fv[3];

        // ---- Kogge-Stone inclusive scan across the 4 t-quads ----
        {
            float Fo = __shfl_up(F, 16), Go = __shfl_up(G, 16);
            if (q >= 1) { G = __builtin_fmaf(F, Go, G); F *= Fo; }
            Fo = __shfl_up(F, 32); Go = __shfl_up(G, 32);
            if (q >= 2) { G = __builtin_fmaf(F, Go, G); F *= Fo; }
        }
        // exclusive prefix for this quad
        float EF = __shfl_up(F, 16), EG = __shfl_up(G, 16);
        if (q == 0) { EF = 1.f; EG = 0.f; }

        // ---- wave summary -> LDS (lanes in last quad hold the wave total) ----
        if (q == 3) sSum[w][nl] = make_float2(F, G);
        __syncthreads();                        // (B) summaries ready; GEMM reads of sA done

        // ---- compose across waves; apply carry ----
        float PF = 1.f, PG = 0.f;               // exclusive prefix over waves
        float TF = 1.f, TG = 0.f;               // total over tile
#pragma unroll
        for (int ww = 0; ww < 4; ++ww) {
            float2 s = sSum[ww][nl];
            if (ww < w) { PG = __builtin_fmaf(s.x, PG, s.y); PF *= s.x; }
            TG = __builtin_fmaf(s.x, TG, s.y); TF *= s.x;
        }
        float cpre = __builtin_fmaf(PF, c_in, PG);   // c at this wave's start
        cpre = __builtin_fmaf(EF, cpre, EG);         // c before this lane's quad

        // ---- epilogue: c_j forward, h = r*tanh(c) + (1-r)*xhw ----
        {
            float cc = cpre;
#pragma unroll
            for (int j = 0; j < 4; ++j) {
                cc = __builtin_fmaf(fv[j], cc, gv[j]);
                int t = trow + j;
                if (t < ttcur) {
                    float xhw;
                    if constexpr (KFAC == 4)
                        xhw = acc[3][j];
                    else
                        xhw = bf2f(xhw_raw[j]);
                    float h = rv[j] * tanh_f(cc) + (1.f - rv[j]) * xhw;
                    hb[(size_t)(t0g + t) * 256 + d0 + nl] = f2bf(h);
                }
            }
        }
        c_in = __builtin_fmaf(TF, c_in, TG);

        // ---- commit next tile to sA (all sA reads finished before (B)) ----
        if (it + 1 < NTIL) {
#pragma unroll
            for (int j = 0; j < NLD; ++j) {
                int idx = j * 256 + tid;
                int r = idx / CPR, cc = idx % CPR;
                *(u32x4*)(&sA[r * LDA + cc * 8]) = xreg[j];
            }
        }
    }
}

// ---------------- output GEMM: out[64000][118] = h1[64000][256] @ Wout + bout ----------------
__global__ __launch_bounds__(256, 2)
void out_gemm_kernel(const unsigned short* __restrict__ h1,
                     const unsigned short* __restrict__ Wt,   // [128][256]
                     const float* __restrict__ bout,
                     float* __restrict__ out) {
    constexpr int K = 256, LDA = 264;
    const int tid = threadIdx.x, lane = tid & 63, w = tid >> 6;
    const int m0 = (blockIdx.x >> 1) * 64;
    const int n0 = (blockIdx.x & 1) * 64;

    __shared__ unsigned short sA[64 * LDA];

    bf16x8 bfrag[4][8];
    {
        const int nl = lane & 15, kq = (lane >> 4) * 8;
#pragma unroll
        for (int nt = 0; nt < 4; ++nt) {
            const unsigned short* src = Wt + (n0 + nt * 16 + nl) * K + kq;
#pragma unroll
            for (int ks = 0; ks < 8; ++ks)
                bfrag[nt][ks] = *(const bf16x8*)(src + ks * 32);
        }
    }
    {
#pragma unroll
        for (int base = 0; base < 2048; base += 256) {
            int idx = base + tid;
            int r = idx >> 5, cc = idx & 31;
            *(u32x4*)&sA[r * LDA + cc * 8] = *(const u32x4*)(h1 + (size_t)(m0 + r) * K + cc * 8);
        }
    }
    __syncthreads();

    f32x4 acc[4];
    f32x4 fz = {0.f, 0.f, 0.f, 0.f};
#pragma unroll
    for (int nt = 0; nt < 4; ++nt) acc[nt] = fz;
    {
        const unsigned short* arow = &sA[(16 * w + (lane & 15)) * LDA + (lane >> 4) * 8];
#pragma unroll
        for (int ks = 0; ks < 8; ++ks) {
            bf16x8 a = *(const bf16x8*)(arow + ks * 32);
#pragma unroll
            for (int nt = 0; nt < 4; ++nt)
                acc[nt] = __builtin_amdgcn_mfma_f32_16x16x32_bf16(a, bfrag[nt][ks], acc[nt], 0, 0, 0);
        }
    }
    {
        const int nl = lane & 15;
        const int rbase = m0 + 16 * w + (lane >> 4) * 4;
#pragma unroll
        for (int nt = 0; nt < 4; ++nt) {
            int col = n0 + nt * 16 + nl;
            if (col < 118) {
                float bo = bout[col];
#pragma unroll
                for (int j = 0; j < 4; ++j)
                    out[(size_t)(rbase + j) * 118 + col] = acc[nt][j] + bo;
            }
        }
    }
}

extern "C" void kernel_launch(void* const* d_in, const int* in_sizes, int n_in,
                              void* d_out, int out_size, void* d_ws, size_t ws_size,
                              hipStream_t stream) {
    const float* seq  = (const float*)d_in[0];
    // d_in[1] = lengths: unused by the reference
    const float* W0   = (const float*)d_in[2];
    const float* b0   = (const float*)d_in[3];
    const float* W1   = (const float*)d_in[4];
    const float* b1   = (const float*)d_in[5];
    const float* Wout = (const float*)d_in[6];
    const float* bout = (const float*)d_in[7];
    float* out = (float*)d_out;

    char* ws = (char*)d_ws;
    size_t off = 0;
    auto alloc = [&](size_t bytes) -> void* {
        void* p = ws + off;
        off = (off + bytes + 255) & ~(size_t)255;
        return p;
    };
    unsigned short* x0p = (unsigned short*)alloc(64000ull * 128 * 2);
    unsigned short* h0b = (unsigned short*)alloc(64000ull * 256 * 2);
    unsigned short* h1b = (unsigned short*)alloc(64000ull * 256 * 2);
    unsigned short* W0t = (unsigned short*)alloc(1024ull * 128 * 2);
    unsigned short* W1t = (unsigned short*)alloc(768ull * 256 * 2);
    unsigned short* Wot = (unsigned short*)alloc(128ull * 256 * 2);
    if (ws_size < off) return;  // workspace too small: bail

    prep_x_kernel<<<dim3(32000), dim3(256), 0, stream>>>(seq, x0p);
    prep_w_kernel<<<dim3(1408), dim3(256), 0, stream>>>(W0, W1, Wout, W0t, W1t, Wot);
    sru_layer_kernel<128, 4><<<dim3(512), dim3(256), 0, stream>>>(x0p, W0t, b0, h0b);
    sru_layer_kernel<256, 3><<<dim3(512), dim3(256), 0, stream>>>(h0b, W1t, b1, h1b);
    out_gemm_kernel<<<dim3(2000), dim3(256), 0, stream>>>(h1b, Wot, bout, out);
}